// Round 1
// baseline (383.321 us; speedup 1.0000x reference)
//
#include <hip/hip_runtime.h>
#include <hip/hip_bf16.h>
#include <math.h>

#define SEQ   65536
#define H2    1024
#define OCHUNKS 64           // o-dimension split for the v reduction
#define OPER   (H2 / OCHUNKS) // 16 o-values per partial block

// ---------------------------------------------------------------------------
// Kernel A1: partial[oc][h] = sum_{o in chunk oc} wv[o] * W[o,h]
// grid (4, OCHUNKS), block 256. Coalesced over h.
// ---------------------------------------------------------------------------
__global__ void reduce_W_partial(const float* __restrict__ W,
                                 const float* __restrict__ wv,
                                 float* __restrict__ partial) {
    int h = blockIdx.x * 256 + threadIdx.x;        // 0..1023
    int oc = blockIdx.y;
    int o0 = oc * OPER;
    float acc = 0.0f;
#pragma unroll
    for (int j = 0; j < OPER; ++j) {
        int o = o0 + j;
        acc += wv[o] * W[(size_t)o * H2 + h];
    }
    partial[(size_t)oc * H2 + h] = acc;
}

// ---------------------------------------------------------------------------
// Kernel A2: v[h] = sum_oc partial[oc][h]
// grid 4, block 256.
// ---------------------------------------------------------------------------
__global__ void reduce_partial_to_v(const float* __restrict__ partial,
                                    float* __restrict__ v) {
    int h = blockIdx.x * 256 + threadIdx.x;
    float acc = 0.0f;
#pragma unroll 8
    for (int oc = 0; oc < OCHUNKS; ++oc)
        acc += partial[(size_t)oc * H2 + h];
    v[h] = acc;
}

// ---------------------------------------------------------------------------
// Kernel B: e[s] = dot(outputs[s,:], v). One wave (64 lanes) per row.
// Each lane: 4 x float4 = 16 floats; wave covers 1024 floats coalesced.
// grid SEQ/4 blocks of 256 (4 waves/block).
// ---------------------------------------------------------------------------
__global__ void row_dot(const float4* __restrict__ outputs,
                        const float4* __restrict__ v4,
                        float* __restrict__ e) {
    int gtid = blockIdx.x * blockDim.x + threadIdx.x;
    int row  = gtid >> 6;          // wave index = row
    int lane = threadIdx.x & 63;

    const float4* rp = outputs + (size_t)row * (H2 / 4);  // 256 float4 per row
    float acc = 0.0f;
#pragma unroll
    for (int i = 0; i < 4; ++i) {
        float4 a = rp[lane + 64 * i];
        float4 b = v4[lane + 64 * i];
        acc += a.x * b.x + a.y * b.y + a.z * b.z + a.w * b.w;
    }
#pragma unroll
    for (int off = 32; off > 0; off >>= 1)
        acc += __shfl_down(acc, off, 64);
    if (lane == 0) e[row] = acc;
}

// ---------------------------------------------------------------------------
// Kernel C: global max + sum(exp(e - max)) over SEQ. One block, 1024 threads.
// stats[0] = max, stats[1] = 1/sum.
// ---------------------------------------------------------------------------
__global__ void softmax_stats(const float* __restrict__ e,
                              float* __restrict__ stats) {
    __shared__ float red[16];
    __shared__ float gmax_sh;
    int tid  = threadIdx.x;
    int wid  = tid >> 6;
    int lane = tid & 63;

    float m = -INFINITY;
    for (int i = tid; i < SEQ; i += 1024) m = fmaxf(m, e[i]);
#pragma unroll
    for (int off = 32; off > 0; off >>= 1)
        m = fmaxf(m, __shfl_down(m, off, 64));
    if (lane == 0) red[wid] = m;
    __syncthreads();
    if (tid == 0) {
        float mm = red[0];
#pragma unroll
        for (int w = 1; w < 16; ++w) mm = fmaxf(mm, red[w]);
        gmax_sh = mm;
    }
    __syncthreads();
    float gmax = gmax_sh;

    float s = 0.0f;
    for (int i = tid; i < SEQ; i += 1024) s += __expf(e[i] - gmax);
#pragma unroll
    for (int off = 32; off > 0; off >>= 1)
        s += __shfl_down(s, off, 64);
    if (lane == 0) red[wid] = s;
    __syncthreads();
    if (tid == 0) {
        float ss = 0.0f;
#pragma unroll
        for (int w = 0; w < 16; ++w) ss += red[w];
        stats[0] = gmax;
        stats[1] = 1.0f / ss;
    }
}

// ---------------------------------------------------------------------------
// Kernel D: out[s] = exp(e[s]-max) * invsum
// ---------------------------------------------------------------------------
__global__ void softmax_norm(const float* __restrict__ e,
                             const float* __restrict__ stats,
                             float* __restrict__ out) {
    int i = blockIdx.x * blockDim.x + threadIdx.x;
    float gmax = stats[0];
    float inv  = stats[1];
    out[i] = __expf(e[i] - gmax) * inv;
}

// ---------------------------------------------------------------------------
extern "C" void kernel_launch(void* const* d_in, const int* in_sizes, int n_in,
                              void* d_out, int out_size, void* d_ws, size_t ws_size,
                              hipStream_t stream) {
    const float* outputs = (const float*)d_in[0];  // [SEQ, H2]
    const float* W       = (const float*)d_in[1];  // [H2, H2]
    // d_in[2] = b  -- unused: softmax is shift-invariant
    const float* wv      = (const float*)d_in[3];  // [1, H2]
    float* out = (float*)d_out;                    // [1,1,SEQ] = SEQ floats

    float* ws = (float*)d_ws;
    float* v       = ws;                         // 1024
    float* partial = ws + H2;                    // 64*1024
    float* e       = ws + H2 + OCHUNKS * H2;     // SEQ
    float* stats   = e + SEQ;                    // 2

    // A1: W column-reduction partials
    reduce_W_partial<<<dim3(4, OCHUNKS), 256, 0, stream>>>(W, wv, partial);
    // A2: fold partials -> v
    reduce_partial_to_v<<<4, 256, 0, stream>>>(partial, v);
    // B: e[s] = outputs[s,:] . v   (the 256 MB memory-bound pass)
    row_dot<<<SEQ / 4, 256, 0, stream>>>((const float4*)outputs,
                                         (const float4*)v, e);
    // C: softmax statistics
    softmax_stats<<<1, 1024, 0, stream>>>(e, stats);
    // D: normalize
    softmax_norm<<<SEQ / 256, 256, 0, stream>>>(e, stats, out);
}

// Round 3
// 377.669 us; speedup vs baseline: 1.0150x; 1.0150x over previous
//
#include <hip/hip_runtime.h>
#include <math.h>

#define SEQ 65536
#define H2  1024

// ---------------------------------------------------------------------------
// A1: partial[oc][h] = sum_{o in chunk oc (16 rows)} wv[o] * W[o,h]
// grid (4, 64), block 256. Coalesced over h.
// ---------------------------------------------------------------------------
__global__ void reduce_W_partial(const float* __restrict__ W,
                                 const float* __restrict__ wv,
                                 float* __restrict__ partial) {
    const int h  = blockIdx.x * 256 + threadIdx.x;
    const int oc = blockIdx.y;
    const int o0 = oc * 16;
    float acc = 0.0f;
#pragma unroll
    for (int j = 0; j < 16; ++j)
        acc += wv[o0 + j] * W[(size_t)(o0 + j) * H2 + h];
    partial[oc * H2 + h] = acc;
}

// ---------------------------------------------------------------------------
// A2: v[h] = sum_oc partial[oc][h].  grid 4, block 256.
// ---------------------------------------------------------------------------
__global__ void fold_v(const float* __restrict__ partial,
                       float* __restrict__ v) {
    const int h = blockIdx.x * 256 + threadIdx.x;
    float acc = 0.0f;
#pragma unroll 8
    for (int oc = 0; oc < 64; ++oc) acc += partial[oc * H2 + h];
    v[h] = acc;
}

// ---------------------------------------------------------------------------
// B: e[s] = dot(outputs[s,:], v) + flash-style per-block (m, s) partials.
// grid 1024 blocks x 256 thr; wave handles 16 rows; 1 KB/row coalesced.
// ---------------------------------------------------------------------------
__global__ void __launch_bounds__(256) row_dot(
        const float4* __restrict__ outputs,   // [SEQ, 256] as float4
        const float4* __restrict__ v4,        // [256] float4
        float* __restrict__ e,                // [SEQ]
        float* __restrict__ bmax,             // [1024]
        float* __restrict__ bsum) {           // [1024]
    const int b    = blockIdx.x;
    const int t    = threadIdx.x;
    const int w    = t >> 6;
    const int lane = t & 63;

    const float4 vr0 = v4[lane];
    const float4 vr1 = v4[lane + 64];
    const float4 vr2 = v4[lane + 128];
    const float4 vr3 = v4[lane + 192];

    const int r0 = b * 64 + w * 16;
    float m = -INFINITY, s = 0.0f, myval = 0.0f;

#pragma unroll 4
    for (int j = 0; j < 16; ++j) {
        const float4* rp = outputs + (size_t)(r0 + j) * 256;
        const float4 a0 = rp[lane];
        const float4 a1 = rp[lane + 64];
        const float4 a2 = rp[lane + 128];
        const float4 a3 = rp[lane + 192];
        float acc = a0.x * vr0.x + a0.y * vr0.y + a0.z * vr0.z + a0.w * vr0.w;
        acc      += a1.x * vr1.x + a1.y * vr1.y + a1.z * vr1.z + a1.w * vr1.w;
        acc      += a2.x * vr2.x + a2.y * vr2.y + a2.z * vr2.z + a2.w * vr2.w;
        acc      += a3.x * vr3.x + a3.y * vr3.y + a3.z * vr3.z + a3.w * vr3.w;
        // butterfly all-reduce: every lane ends with the full row sum
#pragma unroll
        for (int off = 1; off < 64; off <<= 1)
            acc += __shfl_xor(acc, off, 64);
        if (lane == j) myval = acc;
        // online (m, s) update -- wave-uniform
        const float d = acc - m;
        if (d > 0.0f) { s = s * __expf(-d) + 1.0f; m = acc; }
        else          { s += __expf(d); }
    }
    if (lane < 16) e[r0 + lane] = myval;

    __shared__ float lm[4], ls[4];
    if (lane == 0) { lm[w] = m; ls[w] = s; }
    __syncthreads();
    if (t == 0) {
        float M = lm[0], S = ls[0];
#pragma unroll
        for (int i = 1; i < 4; ++i) {
            const float Mn = fmaxf(M, lm[i]);
            S = S * __expf(M - Mn) + ls[i] * __expf(lm[i] - Mn);
            M = Mn;
        }
        bmax[b] = M;
        bsum[b] = S;
    }
}

// ---------------------------------------------------------------------------
// C: merge 1024 (m, s) pairs -> stats[0]=M, stats[1]=1/S.  1 block, 256 thr.
// ---------------------------------------------------------------------------
__global__ void softmax_stats(const float* __restrict__ bmax,
                              const float* __restrict__ bsum,
                              float* __restrict__ stats) {
    const int t = threadIdx.x;
    float M = -INFINITY, S = 0.0f;
#pragma unroll
    for (int i = 0; i < 4; ++i) {
        const int idx = t + 256 * i;
        const float m2 = bmax[idx], s2 = bsum[idx];
        const float Mn = fmaxf(M, m2);
        S = S * __expf(M - Mn) + s2 * __expf(m2 - Mn);
        M = Mn;
    }
    __shared__ float rm[256], rs[256];
    rm[t] = M; rs[t] = S;
    __syncthreads();
    for (int stride = 128; stride > 0; stride >>= 1) {
        if (t < stride) {
            const float M1 = rm[t], S1 = rs[t];
            const float M2 = rm[t + stride], S2 = rs[t + stride];
            const float Mn = fmaxf(M1, M2);
            rm[t] = Mn;
            rs[t] = S1 * __expf(M1 - Mn) + S2 * __expf(M2 - Mn);
        }
        __syncthreads();
    }
    if (t == 0) {
        stats[0] = rm[0];
        stats[1] = 1.0f / rs[0];
    }
}

// ---------------------------------------------------------------------------
// D: out[s] = exp(e[s] - M) * invS.  grid 256, block 256.
// ---------------------------------------------------------------------------
__global__ void softmax_norm(const float* __restrict__ e,
                             const float* __restrict__ stats,
                             float* __restrict__ out) {
    const int i = blockIdx.x * 256 + threadIdx.x;
    out[i] = __expf(e[i] - stats[0]) * stats[1];
}

// ---------------------------------------------------------------------------
extern "C" void kernel_launch(void* const* d_in, const int* in_sizes, int n_in,
                              void* d_out, int out_size, void* d_ws, size_t ws_size,
                              hipStream_t stream) {
    const float* outputs = (const float*)d_in[0];  // [SEQ, H2]
    const float* W       = (const float*)d_in[1];  // [H2, H2]
    // d_in[2] = b  -- unused: softmax is shift-invariant
    const float* wv      = (const float*)d_in[3];  // [1, H2]
    float* out = (float*)d_out;

    float* ws = (float*)d_ws;
    float* v       = ws;                       // 1024
    float* partial = ws + H2;                  // 64*1024
    float* e       = partial + 64 * H2;        // SEQ
    float* bmax    = e + SEQ;                  // 1024
    float* bsum    = bmax + 1024;              // 1024
    float* stats   = bsum + 1024;              // 2

    reduce_W_partial<<<dim3(4, 64), 256, 0, stream>>>(W, wv, partial);
    fold_v<<<4, 256, 0, stream>>>(partial, v);
    row_dot<<<1024, 256, 0, stream>>>((const float4*)outputs,
                                      (const float4*)v, e, bmax, bsum);
    softmax_stats<<<1, 256, 0, stream>>>(bmax, bsum, stats);
    softmax_norm<<<SEQ / 256, 256, 0, stream>>>(e, stats, out);
}

// Round 4
// 377.295 us; speedup vs baseline: 1.0160x; 1.0010x over previous
//
#include <hip/hip_runtime.h>
#include <math.h>

#define SEQ 65536
#define H2  1024

// ---------------------------------------------------------------------------
// A1: partial[oc][h] = sum_{o in chunk oc (16 rows)} wv[o] * W[o,h]
// grid (4, 64), block 256. Coalesced over h; 16 KB of W per block.
// ---------------------------------------------------------------------------
__global__ void reduce_W_partial(const float* __restrict__ W,
                                 const float* __restrict__ wv,
                                 float* __restrict__ partial) {
    const int h  = blockIdx.x * 256 + threadIdx.x;
    const int oc = blockIdx.y;
    const int o0 = oc * 16;
    float acc = 0.0f;
#pragma unroll
    for (int j = 0; j < 16; ++j)
        acc += wv[o0 + j] * W[(size_t)(o0 + j) * H2 + h];
    partial[oc * H2 + h] = acc;
}

// ---------------------------------------------------------------------------
// A2: v[h] = sum_oc partial[oc][h].  grid 4, block 256. Deterministic fold.
// ---------------------------------------------------------------------------
__global__ void fold_v(const float* __restrict__ partial,
                       float* __restrict__ v) {
    const int h = blockIdx.x * 256 + threadIdx.x;
    float acc = 0.0f;
#pragma unroll 8
    for (int oc = 0; oc < 64; ++oc) acc += partial[oc * H2 + h];
    v[h] = acc;
}

// ---------------------------------------------------------------------------
// B: e[s] = dot(outputs[s,:], v) + flash-style per-block (m, s) partials.
// grid 1024 blocks x 256 thr; wave handles 16 rows; 1 KB/row coalesced.
// This is the BW carrier: 256 MB streaming read.
// ---------------------------------------------------------------------------
__global__ void __launch_bounds__(256) row_dot(
        const float4* __restrict__ outputs,   // [SEQ, 256] as float4
        const float4* __restrict__ v4,        // [256] float4
        float* __restrict__ e,                // [SEQ]
        float* __restrict__ bmax,             // [1024]
        float* __restrict__ bsum) {           // [1024]
    const int b    = blockIdx.x;
    const int t    = threadIdx.x;
    const int w    = t >> 6;
    const int lane = t & 63;

    const float4 vr0 = v4[lane];
    const float4 vr1 = v4[lane + 64];
    const float4 vr2 = v4[lane + 128];
    const float4 vr3 = v4[lane + 192];

    const int r0 = b * 64 + w * 16;
    float m = -INFINITY, s = 0.0f, myval = 0.0f;

#pragma unroll 4
    for (int j = 0; j < 16; ++j) {
        const float4* rp = outputs + (size_t)(r0 + j) * 256;
        const float4 a0 = rp[lane];
        const float4 a1 = rp[lane + 64];
        const float4 a2 = rp[lane + 128];
        const float4 a3 = rp[lane + 192];
        float acc = a0.x * vr0.x + a0.y * vr0.y + a0.z * vr0.z + a0.w * vr0.w;
        acc      += a1.x * vr1.x + a1.y * vr1.y + a1.z * vr1.z + a1.w * vr1.w;
        acc      += a2.x * vr2.x + a2.y * vr2.y + a2.z * vr2.z + a2.w * vr2.w;
        acc      += a3.x * vr3.x + a3.y * vr3.y + a3.z * vr3.z + a3.w * vr3.w;
        // butterfly all-reduce: every lane ends with the full row sum
#pragma unroll
        for (int off = 1; off < 64; off <<= 1)
            acc += __shfl_xor(acc, off, 64);
        if (lane == j) myval = acc;
        // online (m, s) update -- wave-uniform
        const float d = acc - m;
        if (d > 0.0f) { s = s * __expf(-d) + 1.0f; m = acc; }
        else          { s += __expf(d); }
    }
    if (lane < 16) e[r0 + lane] = myval;

    __shared__ float lm[4], ls[4];
    if (lane == 0) { lm[w] = m; ls[w] = s; }
    __syncthreads();
    if (t == 0) {
        float M = lm[0], S = ls[0];
#pragma unroll
        for (int i = 1; i < 4; ++i) {
            const float Mn = fmaxf(M, lm[i]);
            S = S * __expf(M - Mn) + ls[i] * __expf(lm[i] - Mn);
            M = Mn;
        }
        bmax[b] = M;
        bsum[b] = S;
    }
}

// ---------------------------------------------------------------------------
// C (fused): every block redundantly merges the 1024 (m,s) pairs (8 KB,
// L3-hot), then normalizes its 256 rows. grid 256, block 256.
// Replaces the separate softmax_stats dispatch.
// ---------------------------------------------------------------------------
__global__ void __launch_bounds__(256) softmax_norm_fused(
        const float* __restrict__ e,
        const float* __restrict__ bmax,
        const float* __restrict__ bsum,
        float* __restrict__ out) {
    const int t = threadIdx.x;
    float M = -INFINITY, S = 0.0f;
#pragma unroll
    for (int i = 0; i < 4; ++i) {
        const int idx = t + 256 * i;               // coalesced
        const float m2 = bmax[idx], s2 = bsum[idx];
        const float Mn = fmaxf(M, m2);
        S = S * __expf(M - Mn) + s2 * __expf(m2 - Mn);
        M = Mn;
    }
    __shared__ float rm[256], rs[256];
    rm[t] = M; rs[t] = S;
    __syncthreads();
    for (int stride = 128; stride > 0; stride >>= 1) {
        if (t < stride) {
            const float M1 = rm[t], S1 = rs[t];
            const float M2 = rm[t + stride], S2 = rs[t + stride];
            const float Mn = fmaxf(M1, M2);
            rm[t] = Mn;
            rs[t] = S1 * __expf(M1 - Mn) + S2 * __expf(M2 - Mn);
        }
        __syncthreads();
    }
    const float Mg  = rm[0];
    const float inv = 1.0f / rs[0];

    const int i = blockIdx.x * 256 + t;
    out[i] = __expf(e[i] - Mg) * inv;
}

// ---------------------------------------------------------------------------
extern "C" void kernel_launch(void* const* d_in, const int* in_sizes, int n_in,
                              void* d_out, int out_size, void* d_ws, size_t ws_size,
                              hipStream_t stream) {
    const float* outputs = (const float*)d_in[0];  // [SEQ, H2]
    const float* W       = (const float*)d_in[1];  // [H2, H2]
    // d_in[2] = b  -- unused: softmax is shift-invariant
    const float* wv      = (const float*)d_in[3];  // [1, H2]
    float* out = (float*)d_out;

    float* ws = (float*)d_ws;
    float* v       = ws;                       // 1024
    float* partial = ws + H2;                  // 64*1024
    float* e       = partial + 64 * H2;        // SEQ
    float* bmax    = e + SEQ;                  // 1024
    float* bsum    = bmax + 1024;              // 1024

    reduce_W_partial<<<dim3(4, 64), 256, 0, stream>>>(W, wv, partial);
    fold_v<<<4, 256, 0, stream>>>(partial, v);
    row_dot<<<1024, 256, 0, stream>>>((const float4*)outputs,
                                      (const float4*)v, e, bmax, bsum);
    softmax_norm_fused<<<SEQ / 256, 256, 0, stream>>>(e, bmax, bsum, out);
}